// Round 2
// baseline (2060.726 us; speedup 1.0000x reference)
//
#include <hip/hip_runtime.h>
#include <math.h>

#define SEQ    4096
#define DMODEL 1024
#define NHEADS 16
#define DK     64

// ---------------------------------------------------------------------------
// GEMM: out[M][N] = X[M][K] * W[N][K]^T   (einsum 'sd,od->so')
// 64x64 output tile per block, 256 threads, 4x4 micro-tile per thread.
// ---------------------------------------------------------------------------
__global__ __launch_bounds__(256) void gemm_xwt_kernel(
    const float* __restrict__ X, const float* __restrict__ W,
    float* __restrict__ out, int M, int N, int K)
{
    __shared__ float As[32][68];   // As[k][m] = X[m0+m][k0+k]
    __shared__ float Bs[32][68];   // Bs[k][n] = W[n0+n][k0+k]

    const int t  = threadIdx.x;
    const int tx = t & 15;         // n-direction (4 cols each)
    const int ty = t >> 4;         // m-direction (4 rows each)
    const int m0 = blockIdx.y * 64;
    const int n0 = blockIdx.x * 64;

    const int lrow = t >> 3;        // 0..31
    const int lc4  = (t & 7) * 4;   // 0,4,...,28

    float acc[4][4];
#pragma unroll
    for (int i = 0; i < 4; ++i)
#pragma unroll
        for (int j = 0; j < 4; ++j) acc[i][j] = 0.f;

    for (int k0 = 0; k0 < K; k0 += 32) {
        float4 x0 = *(const float4*)&X[(size_t)(m0 + lrow) * K + k0 + lc4];
        float4 x1 = *(const float4*)&X[(size_t)(m0 + lrow + 32) * K + k0 + lc4];
        float4 w0 = *(const float4*)&W[(size_t)(n0 + lrow) * K + k0 + lc4];
        float4 w1 = *(const float4*)&W[(size_t)(n0 + lrow + 32) * K + k0 + lc4];

        __syncthreads();   // protect previous iteration's reads
        As[lc4+0][lrow]      = x0.x; As[lc4+1][lrow]      = x0.y;
        As[lc4+2][lrow]      = x0.z; As[lc4+3][lrow]      = x0.w;
        As[lc4+0][lrow+32]   = x1.x; As[lc4+1][lrow+32]   = x1.y;
        As[lc4+2][lrow+32]   = x1.z; As[lc4+3][lrow+32]   = x1.w;
        Bs[lc4+0][lrow]      = w0.x; Bs[lc4+1][lrow]      = w0.y;
        Bs[lc4+2][lrow]      = w0.z; Bs[lc4+3][lrow]      = w0.w;
        Bs[lc4+0][lrow+32]   = w1.x; Bs[lc4+1][lrow+32]   = w1.y;
        Bs[lc4+2][lrow+32]   = w1.z; Bs[lc4+3][lrow+32]   = w1.w;
        __syncthreads();

#pragma unroll
        for (int k = 0; k < 32; ++k) {
            float4 a = *(const float4*)&As[k][ty * 4];
            float4 b = *(const float4*)&Bs[k][tx * 4];
            acc[0][0] += a.x*b.x; acc[0][1] += a.x*b.y; acc[0][2] += a.x*b.z; acc[0][3] += a.x*b.w;
            acc[1][0] += a.y*b.x; acc[1][1] += a.y*b.y; acc[1][2] += a.y*b.z; acc[1][3] += a.y*b.w;
            acc[2][0] += a.z*b.x; acc[2][1] += a.z*b.y; acc[2][2] += a.z*b.z; acc[2][3] += a.z*b.w;
            acc[3][0] += a.w*b.x; acc[3][1] += a.w*b.y; acc[3][2] += a.w*b.z; acc[3][3] += a.w*b.w;
        }
    }

#pragma unroll
    for (int i = 0; i < 4; ++i) {
        float4 v = make_float4(acc[i][0], acc[i][1], acc[i][2], acc[i][3]);
        *(float4*)&out[(size_t)(m0 + ty * 4 + i) * N + n0 + tx * 4] = v;
    }
}

// ---------------------------------------------------------------------------
// RoPE applied in-place to Q and K. Layout [S][H*DK]; interleaved pairs.
// ---------------------------------------------------------------------------
__global__ void rope_kernel(float* __restrict__ Q, float* __restrict__ K)
{
    int idx = blockIdx.x * blockDim.x + threadIdx.x;  // S*H*(DK/2) = 2M
    if (idx >= SEQ * NHEADS * (DK / 2)) return;
    int i = idx & 31;                // freq index 0..31
    int h = (idx >> 5) & (NHEADS - 1);
    int s = idx >> 9;                // 0..4095

    double expo = -((double)(2 * i) / (double)DK);
    double inv  = pow(10000.0, expo);
    double ang  = fmod((double)s * inv, 6.283185307179586476925286766559);
    float c  = (float)cos(ang);
    float sn = (float)sin(ang);

    size_t base = (size_t)s * DMODEL + h * DK + 2 * i;
    float qe = Q[base], qo = Q[base + 1];
    Q[base]     = c * qe - sn * qo;
    Q[base + 1] = sn * qe + c * qo;
    float ke = K[base], ko = K[base + 1];
    K[base]     = c * ke - sn * ko;
    K[base + 1] = sn * ke + c * ko;
}

// ---------------------------------------------------------------------------
// Causal flash attention, fp32. One block per (head, 64-row q tile).
// 256 threads: thread t -> q-row r = t>>2, column group cj = t&3.
// Each thread holds the FULL 64-dim q row (4x replicated across the row's
// 4 lanes) and computes complete dot products for columns c = 4j+cj.
// ---------------------------------------------------------------------------
__global__ __launch_bounds__(256) void attn_kernel(
    const float* __restrict__ Q, const float* __restrict__ K,
    const float* __restrict__ V, float* __restrict__ ctx)
{
    __shared__ float Ks[64][68];
    __shared__ float Vs[64][68];
    __shared__ float Ss[64][65];

    const int h  = blockIdx.y;
    const int qt = gridDim.x - 1 - blockIdx.x;   // long blocks first
    const int q0 = qt * 64;
    const int t  = threadIdx.x;
    const int r  = t >> 2;     // 0..63 q row within tile
    const int cj = t & 3;      // column group (c = 4j + cj)

    // Full q row in registers (replicated over the 4 lanes of this row)
    float qreg[64];
    {
        const float* qp = &Q[(size_t)(q0 + r) * DMODEL + h * DK];
#pragma unroll
        for (int i = 0; i < 16; ++i) {
            float4 v = *(const float4*)&qp[i * 4];
            qreg[i*4+0] = v.x; qreg[i*4+1] = v.y; qreg[i*4+2] = v.z; qreg[i*4+3] = v.w;
        }
    }

    float o[16];
#pragma unroll
    for (int j = 0; j < 16; ++j) o[j] = 0.f;
    float m = -3.0e38f, l = 0.f;
    const float scale = 0.125f;   // 1/sqrt(64)

    for (int kt = 0; kt <= qt; ++kt) {
        const int k0 = kt * 64;
        __syncthreads();   // previous tile's Ks/Vs/Ss reads are done
        for (int idx = t; idx < 64 * 16; idx += 256) {
            int row = idx >> 4, c4 = (idx & 15) * 4;
            *(float4*)&Ks[row][c4] = *(const float4*)&K[(size_t)(k0 + row) * DMODEL + h * DK + c4];
            *(float4*)&Vs[row][c4] = *(const float4*)&V[(size_t)(k0 + row) * DMODEL + h * DK + c4];
        }
        __syncthreads();

        // ---- scores: full dot products for columns c = 4*j + cj ----
        float sc[16];
#pragma unroll
        for (int j = 0; j < 16; ++j) sc[j] = 0.f;
#pragma unroll
        for (int i = 0; i < 16; ++i) {
#pragma unroll
            for (int j = 0; j < 16; ++j) {
                float4 kv = *(const float4*)&Ks[4 * j + cj][i * 4];
                sc[j] += qreg[i*4+0]*kv.x + qreg[i*4+1]*kv.y
                       + qreg[i*4+2]*kv.z + qreg[i*4+3]*kv.w;
            }
        }
        // scale + causal mask
#pragma unroll
        for (int j = 0; j < 16; ++j) {
            int c = 4 * j + cj;
            sc[j] *= scale;
            if (k0 + c > q0 + r) sc[j] = -3.0e38f;
        }
        // row max: 16 local columns, then across the row's 4 lanes
        float mx = sc[0];
#pragma unroll
        for (int j = 1; j < 16; ++j) mx = fmaxf(mx, sc[j]);
        mx = fmaxf(mx, __shfl_xor(mx, 1));
        mx = fmaxf(mx, __shfl_xor(mx, 2));
        float m_new = fmaxf(m, mx);
        float alpha = __expf(m - m_new);

        float psum = 0.f;
#pragma unroll
        for (int j = 0; j < 16; ++j) {
            float p = __expf(sc[j] - m_new);
            Ss[r][4 * j + cj] = p;
            psum += p;
        }
        psum += __shfl_xor(psum, 1);
        psum += __shfl_xor(psum, 2);
        l = l * alpha + psum;
        m = m_new;
#pragma unroll
        for (int j = 0; j < 16; ++j) o[j] *= alpha;
        __syncthreads();   // Ss visible to all lanes of the row

        // ---- PV: o[dims cj*16 .. +15] += sum_c P[r][c] * V[c][dim] ----
#pragma unroll 8
        for (int c = 0; c < 64; ++c) {
            float p = Ss[r][c];
#pragma unroll
            for (int j4 = 0; j4 < 4; ++j4) {
                float4 vv = *(const float4*)&Vs[c][cj * 16 + j4 * 4];
                o[j4*4+0] += p * vv.x; o[j4*4+1] += p * vv.y;
                o[j4*4+2] += p * vv.z; o[j4*4+3] += p * vv.w;
            }
        }
    }

    float inv_l = 1.f / l;
#pragma unroll
    for (int j4 = 0; j4 < 4; ++j4) {
        float4 ov = make_float4(o[j4*4+0]*inv_l, o[j4*4+1]*inv_l,
                                o[j4*4+2]*inv_l, o[j4*4+3]*inv_l);
        *(float4*)&ctx[(size_t)(q0 + r) * DMODEL + h * DK + cj * 16 + j4 * 4] = ov;
    }
}

// ---------------------------------------------------------------------------
extern "C" void kernel_launch(void* const* d_in, const int* in_sizes, int n_in,
                              void* d_out, int out_size, void* d_ws, size_t ws_size,
                              hipStream_t stream)
{
    const float* x  = (const float*)d_in[0];
    const float* wq = (const float*)d_in[1];
    const float* wk = (const float*)d_in[2];
    const float* wv = (const float*)d_in[3];
    const float* wo = (const float*)d_in[4];
    float* out = (float*)d_out;

    const size_t NELEM = (size_t)SEQ * DMODEL;   // 4M floats = 16 MB
    float* ws = (float*)d_ws;
    float* Qb = ws;
    float* Kb = ws + NELEM;
    float* Vb = ws + 2 * NELEM;
    float* Cb = ws + 3 * NELEM;

    dim3 gblk(256);
    dim3 ggrid(DMODEL / 64, SEQ / 64);   // (16, 64)
    hipLaunchKernelGGL(gemm_xwt_kernel, ggrid, gblk, 0, stream, x, wq, Qb, SEQ, DMODEL, DMODEL);
    hipLaunchKernelGGL(gemm_xwt_kernel, ggrid, gblk, 0, stream, x, wk, Kb, SEQ, DMODEL, DMODEL);
    hipLaunchKernelGGL(gemm_xwt_kernel, ggrid, gblk, 0, stream, x, wv, Vb, SEQ, DMODEL, DMODEL);

    int nrope = SEQ * NHEADS * (DK / 2);
    hipLaunchKernelGGL(rope_kernel, dim3((nrope + 255) / 256), dim3(256), 0, stream, Qb, Kb);

    dim3 agrid(SEQ / 64, NHEADS);        // (64, 16)
    hipLaunchKernelGGL(attn_kernel, agrid, dim3(256), 0, stream, Qb, Kb, Vb, Cb);

    hipLaunchKernelGGL(gemm_xwt_kernel, ggrid, gblk, 0, stream, Cb, wo, out, SEQ, DMODEL, DMODEL);
}

// Round 3
// 451.635 us; speedup vs baseline: 4.5628x; 4.5628x over previous
//
#include <hip/hip_runtime.h>
#include <math.h>

#define SEQ    4096
#define DMODEL 1024
#define NHEADS 16
#define DK     64

typedef unsigned short u16;
typedef short bh8 __attribute__((ext_vector_type(8)));   // 8 x bf16 (4 VGPRs)
typedef float f4  __attribute__((ext_vector_type(4)));   // 4 x fp32 acc

__device__ __forceinline__ u16 f2b(float f) {
    union { float f; unsigned u; } v; v.f = f;
    unsigned u = v.u;
    return (u16)((u + 0x7FFFu + ((u >> 16) & 1u)) >> 16);   // RNE
}
__device__ __forceinline__ float b2f(u16 b) {
    union { unsigned u; float f; } v; v.u = ((unsigned)b) << 16;
    return v.f;
}

// ---------------------------------------------------------------------------
// fp32 -> bf16 bulk convert (8 elements/thread)
// ---------------------------------------------------------------------------
__global__ void cvt_kernel(const float* __restrict__ in, u16* __restrict__ out, int n8)
{
    int i = blockIdx.x * blockDim.x + threadIdx.x;
    if (i >= n8) return;
    const float4* p = (const float4*)in + (size_t)i * 2;
    float4 a = p[0], b = p[1];
    __align__(16) u16 r[8] = { f2b(a.x), f2b(a.y), f2b(a.z), f2b(a.w),
                               f2b(b.x), f2b(b.y), f2b(b.z), f2b(b.w) };
    *(uint4*)(out + (size_t)i * 8) = *(const uint4*)r;
}

// ---------------------------------------------------------------------------
// bf16 MFMA GEMM (bt-form): out[M][N] = A[M][K] * B[N][K]^T
// 128x128 tile, BK=32, 4 waves, each wave 64x64 via 4x4 mfma_16x16x32_bf16.
// Staging via global_load_lds width=16 (m97 structure).
// OUT_BF16: 1 -> write bf16, 0 -> write fp32.
// ---------------------------------------------------------------------------
template<int OUT_BF16>
__global__ __launch_bounds__(256) void gemm_bt(
    const u16* __restrict__ A, const u16* __restrict__ B,
    void* __restrict__ out, int M, int N, int K)
{
    __shared__ __align__(16) u16 As[128 * 32];   // [row][k] no pad (load_lds order)
    __shared__ __align__(16) u16 Bs[128 * 32];

    const int t    = threadIdx.x;
    const int w    = t >> 6, lane = t & 63;
    const int quad = lane >> 4, l16 = lane & 15;
    const int wm   = w >> 1,  wn  = w & 1;
    const int m0   = blockIdx.y * 128, n0 = blockIdx.x * 128;
    const int lr   = lane >> 2;          // row within 16-row chunk
    const int lc   = (lane & 3) * 8;     // element col within 32

    f4 acc[4][4];
#pragma unroll
    for (int i = 0; i < 4; ++i)
#pragma unroll
        for (int j = 0; j < 4; ++j) { f4 z = {0.f,0.f,0.f,0.f}; acc[i][j] = z; }

    const int c0 = 2 * w, c1 = 2 * w + 1;

    for (int k0 = 0; k0 < K; k0 += 32) {
        // wave w stages 1KB chunks c0,c1 of A and B (16 rows x 64B each)
        __builtin_amdgcn_global_load_lds(
            (const __attribute__((address_space(1))) unsigned int*)(A + (size_t)(m0 + c0*16 + lr)*K + k0 + lc),
            (__attribute__((address_space(3))) unsigned int*)(As + c0*512), 16, 0, 0);
        __builtin_amdgcn_global_load_lds(
            (const __attribute__((address_space(1))) unsigned int*)(A + (size_t)(m0 + c1*16 + lr)*K + k0 + lc),
            (__attribute__((address_space(3))) unsigned int*)(As + c1*512), 16, 0, 0);
        __builtin_amdgcn_global_load_lds(
            (const __attribute__((address_space(1))) unsigned int*)(B + (size_t)(n0 + c0*16 + lr)*K + k0 + lc),
            (__attribute__((address_space(3))) unsigned int*)(Bs + c0*512), 16, 0, 0);
        __builtin_amdgcn_global_load_lds(
            (const __attribute__((address_space(1))) unsigned int*)(B + (size_t)(n0 + c1*16 + lr)*K + k0 + lc),
            (__attribute__((address_space(3))) unsigned int*)(Bs + c1*512), 16, 0, 0);
        __syncthreads();   // drains vmcnt before barrier (compiler-inserted)

        bh8 af[4], bf_[4];
#pragma unroll
        for (int i = 0; i < 4; ++i)
            af[i] = *(const bh8*)&As[(wm*64 + i*16 + l16)*32 + quad*8];
#pragma unroll
        for (int j = 0; j < 4; ++j)
            bf_[j] = *(const bh8*)&Bs[(wn*64 + j*16 + l16)*32 + quad*8];
#pragma unroll
        for (int i = 0; i < 4; ++i)
#pragma unroll
            for (int j = 0; j < 4; ++j)
                acc[i][j] = __builtin_amdgcn_mfma_f32_16x16x32_bf16(af[i], bf_[j], acc[i][j], 0, 0, 0);
        __syncthreads();   // protect LDS from next iteration's staging
    }

    // epilogue: C/D layout col=lane&15, row=quad*4+reg  [m89/m91 verified]
#pragma unroll
    for (int i = 0; i < 4; ++i) {
        const int row = m0 + wm*64 + i*16 + quad*4;
#pragma unroll
        for (int j = 0; j < 4; ++j) {
            const int col = n0 + wn*64 + j*16 + l16;
#pragma unroll
            for (int r = 0; r < 4; ++r) {
                if (OUT_BF16)
                    ((u16*)out)[(size_t)(row + r) * N + col] = f2b(acc[i][j][r]);
                else
                    ((float*)out)[(size_t)(row + r) * N + col] = acc[i][j][r];
            }
        }
    }
}

// ---------------------------------------------------------------------------
// RoPE on bf16 Q,K [s][1024] and repack to head-major [h][s][64] bf16.
// Angle in double (pos<=4095), sin/cos in float after range reduction.
// ---------------------------------------------------------------------------
__global__ void rope_pack_kernel(const u16* __restrict__ Qf, const u16* __restrict__ Kf,
                                 u16* __restrict__ Qh, u16* __restrict__ Kh)
{
    int idx = blockIdx.x * blockDim.x + threadIdx.x;   // S*H*32
    if (idx >= SEQ * NHEADS * 32) return;
    int i = idx & 31;
    int h = (idx >> 5) & (NHEADS - 1);
    int s = idx >> 9;

    double inv = pow(10000.0, -((double)(2 * i) / (double)DK));
    double ang = fmod((double)s * inv, 6.283185307179586476925286766559);
    float fa = (float)ang;
    float c = cosf(fa), sn = sinf(fa);

    size_t src = (size_t)s * DMODEL + h * DK + 2 * i;
    float qe = b2f(Qf[src]), qo = b2f(Qf[src + 1]);
    float ke = b2f(Kf[src]), ko = b2f(Kf[src + 1]);

    size_t dst = ((size_t)h * SEQ + s) * DK + 2 * i;
    __align__(4) u16 q2[2] = { f2b(c*qe - sn*qo), f2b(sn*qe + c*qo) };
    __align__(4) u16 k2[2] = { f2b(c*ke - sn*ko), f2b(sn*ke + c*ko) };
    *(unsigned int*)(Qh + dst) = *(const unsigned int*)q2;
    *(unsigned int*)(Kh + dst) = *(const unsigned int*)k2;
}

// ---------------------------------------------------------------------------
// V bf16 [s][1024] -> transposed [h][d=64][s=4096] bf16 (LDS tile transpose)
// ---------------------------------------------------------------------------
__global__ __launch_bounds__(256) void pack_v_kernel(const u16* __restrict__ Vf, u16* __restrict__ Vt)
{
    __shared__ __align__(16) u16 Ts[64 * 72];
    const int h = blockIdx.y, s0 = blockIdx.x * 64;
    const int t = threadIdx.x;
#pragma unroll
    for (int i2 = 0; i2 < 2; ++i2) {
        int chunk = t + 256 * i2;          // 0..511
        int sr = chunk >> 3, o8 = (chunk & 7) * 8;
        __align__(16) u16 tmp[8];
        *(uint4*)tmp = *(const uint4*)&Vf[(size_t)(s0 + sr) * DMODEL + h * DK + o8];
#pragma unroll
        for (int jj = 0; jj < 8; ++jj) Ts[(o8 + jj) * 72 + sr] = tmp[jj];
    }
    __syncthreads();
#pragma unroll
    for (int i2 = 0; i2 < 2; ++i2) {
        int chunk = t + 256 * i2;
        int d = chunk >> 3, o8 = (chunk & 7) * 8;
        *(uint4*)&Vt[((size_t)h * DK + d) * SEQ + s0 + o8] = *(const uint4*)&Ts[d * 72 + o8];
    }
}

// ---------------------------------------------------------------------------
// MFMA flash attention. Block = (qtile of 64 rows, head); 4 waves x 16 rows.
// Q,K: [h][s][64] bf16; Vt: [h][64][s] bf16; ctx out: [s][1024] bf16.
// ---------------------------------------------------------------------------
__global__ __launch_bounds__(256) void attn_mfma_kernel(
    const u16* __restrict__ Qh, const u16* __restrict__ Kh,
    const u16* __restrict__ Vt, u16* __restrict__ ctx)
{
    __shared__ __align__(16) u16 Ks[64 * 72];      // [key][d]
    __shared__ __align__(16) u16 Vs[64 * 72];      // [d][key]  (transposed V)
    __shared__ __align__(16) u16 Ps[4][16 * 72];   // per-wave P, [qrow][key]

    const int h  = blockIdx.y;
    const int qt = gridDim.x - 1 - blockIdx.x;     // long blocks first
    const int q0 = qt * 64;
    const int t  = threadIdx.x;
    const int w  = t >> 6, lane = t & 63;
    const int quad = lane >> 4, l16 = lane & 15;

    // Q A-fragments: A[m=l16][k=quad*8+j]  [m89 layout]
    bh8 qa0, qa1;
    {
        const u16* qrow = Qh + ((size_t)h * SEQ + q0 + w * 16 + l16) * DK;
        qa0 = *(const bh8*)(qrow + quad * 8);
        qa1 = *(const bh8*)(qrow + 32 + quad * 8);
    }

    f4 o[4];
    float mrun[4], lrun[4];
#pragma unroll
    for (int j = 0; j < 4; ++j) { f4 z = {0.f,0.f,0.f,0.f}; o[j] = z; }
#pragma unroll
    for (int r = 0; r < 4; ++r) { mrun[r] = -3.0e38f; lrun[r] = 0.f; }

    const float SCL2 = 0.125f * 1.44269504088896340736f;   // scale * log2(e)

    for (int kt = 0; kt <= qt; ++kt) {
        const int k0 = kt * 64;
        __syncthreads();   // prev iteration's reads of Ks/Vs done
#pragma unroll
        for (int i2 = 0; i2 < 2; ++i2) {
            int chunk = t + 256 * i2;           // 0..511
            int row = chunk >> 3, o8 = (chunk & 7) * 8;
            *(uint4*)&Ks[row * 72 + o8] = *(const uint4*)&Kh[((size_t)h * SEQ + k0 + row) * DK + o8];
            *(uint4*)&Vs[row * 72 + o8] = *(const uint4*)&Vt[((size_t)h * DK + row) * SEQ + k0 + o8];
        }
        __syncthreads();

        // ---- scores S = Q K^T (bt-form), 4 key-blocks x 2 K=32 steps ----
        float sv[4][4];
#pragma unroll
        for (int kb = 0; kb < 4; ++kb) {
            bh8 kf0 = *(const bh8*)&Ks[(kb * 16 + l16) * 72 + quad * 8];
            bh8 kf1 = *(const bh8*)&Ks[(kb * 16 + l16) * 72 + 32 + quad * 8];
            f4 a = {0.f,0.f,0.f,0.f};
            a = __builtin_amdgcn_mfma_f32_16x16x32_bf16(qa0, kf0, a, 0, 0, 0);
            a = __builtin_amdgcn_mfma_f32_16x16x32_bf16(qa1, kf1, a, 0, 0, 0);
#pragma unroll
            for (int r = 0; r < 4; ++r) sv[kb][r] = a[r] * SCL2;
        }
        // causal mask only on the diagonal tile
        if (kt == qt) {
#pragma unroll
            for (int kb = 0; kb < 4; ++kb)
#pragma unroll
                for (int r = 0; r < 4; ++r)
                    if (kb * 16 + l16 > w * 16 + quad * 4 + r) sv[kb][r] = -1.0e30f;
        }

        // ---- online softmax (rows live in 16-lane groups; xor masks <16) ----
        float alpha[4];
#pragma unroll
        for (int r = 0; r < 4; ++r) {
            float mx = fmaxf(fmaxf(sv[0][r], sv[1][r]), fmaxf(sv[2][r], sv[3][r]));
            mx = fmaxf(mx, __shfl_xor(mx, 1));
            mx = fmaxf(mx, __shfl_xor(mx, 2));
            mx = fmaxf(mx, __shfl_xor(mx, 4));
            mx = fmaxf(mx, __shfl_xor(mx, 8));
            float mn = fmaxf(mrun[r], mx);
            alpha[r] = exp2f(mrun[r] - mn);
            mrun[r] = mn;
            float ps = 0.f;
#pragma unroll
            for (int kb = 0; kb < 4; ++kb) {
                float p = exp2f(sv[kb][r] - mn);
                Ps[w][(quad * 4 + r) * 72 + kb * 16 + l16] = f2b(p);  // C-layout -> LDS
                ps += p;
            }
            ps += __shfl_xor(ps, 1);
            ps += __shfl_xor(ps, 2);
            ps += __shfl_xor(ps, 4);
            ps += __shfl_xor(ps, 8);
            lrun[r] = lrun[r] * alpha[r] + ps;
        }
#pragma unroll
        for (int j = 0; j < 4; ++j) {
            f4 oj = o[j];
#pragma unroll
            for (int r = 0; r < 4; ++r) oj[r] *= alpha[r];
            o[j] = oj;
        }

        // ---- PV: P (A-layout from LDS) x V^T-tile (B from Vs) ----
        bh8 pa0 = *(const bh8*)&Ps[w][l16 * 72 + quad * 8];
        bh8 pa1 = *(const bh8*)&Ps[w][l16 * 72 + 32 + quad * 8];
#pragma unroll
        for (int j = 0; j < 4; ++j) {
            bh8 v0 = *(const bh8*)&Vs[(j * 16 + l16) * 72 + quad * 8];
            bh8 v1 = *(const bh8*)&Vs[(j * 16 + l16) * 72 + 32 + quad * 8];
            o[j] = __builtin_amdgcn_mfma_f32_16x16x32_bf16(pa0, v0, o[j], 0, 0, 0);
            o[j] = __builtin_amdgcn_mfma_f32_16x16x32_bf16(pa1, v1, o[j], 0, 0, 0);
        }
    }

    float inv[4];
#pragma unroll
    for (int r = 0; r < 4; ++r) inv[r] = 1.f / lrun[r];
#pragma unroll
    for (int j = 0; j < 4; ++j)
#pragma unroll
        for (int r = 0; r < 4; ++r)
            ctx[(size_t)(q0 + w * 16 + quad * 4 + r) * DMODEL + h * DK + j * 16 + l16] =
                f2b(o[j][r] * inv[r]);
}

// ---------------------------------------------------------------------------
extern "C" void kernel_launch(void* const* d_in, const int* in_sizes, int n_in,
                              void* d_out, int out_size, void* d_ws, size_t ws_size,
                              hipStream_t stream)
{
    const float* x  = (const float*)d_in[0];
    const float* wq = (const float*)d_in[1];
    const float* wk = (const float*)d_in[2];
    const float* wv = (const float*)d_in[3];
    const float* wo = (const float*)d_in[4];
    float* out = (float*)d_out;

    char* ws = (char*)d_ws;
    const size_t MB = 1u << 20;
    u16* xb   = (u16*)(ws);              // 8 MB
    u16* wqb  = (u16*)(ws + 8  * MB);    // 2 MB
    u16* wkb  = (u16*)(ws + 10 * MB);
    u16* wvb  = (u16*)(ws + 12 * MB);
    u16* wob  = (u16*)(ws + 14 * MB);
    u16* Qf   = (u16*)(ws + 16 * MB);    // 8 MB  [s][1024] bf16
    u16* Kf   = (u16*)(ws + 24 * MB);
    u16* Vf   = (u16*)(ws + 32 * MB);
    u16* Qh   = (u16*)(ws + 40 * MB);    // [h][s][64]
    u16* Kh   = (u16*)(ws + 48 * MB);
    u16* Vtb  = (u16*)(ws + 56 * MB);    // [h][64][s]
    u16* ctxb = Qf;                      // Qf dead after rope_pack (stream-ordered)

    cvt_kernel<<<2048, 256, 0, stream>>>(x,  xb,  SEQ * DMODEL / 8);
    cvt_kernel<<<512,  256, 0, stream>>>(wq, wqb, DMODEL * DMODEL / 8);
    cvt_kernel<<<512,  256, 0, stream>>>(wk, wkb, DMODEL * DMODEL / 8);
    cvt_kernel<<<512,  256, 0, stream>>>(wv, wvb, DMODEL * DMODEL / 8);
    cvt_kernel<<<512,  256, 0, stream>>>(wo, wob, DMODEL * DMODEL / 8);

    dim3 gg(DMODEL / 128, SEQ / 128);    // (8, 32)
    gemm_bt<1><<<gg, 256, 0, stream>>>(xb, wqb, Qf, SEQ, DMODEL, DMODEL);
    gemm_bt<1><<<gg, 256, 0, stream>>>(xb, wkb, Kf, SEQ, DMODEL, DMODEL);
    gemm_bt<1><<<gg, 256, 0, stream>>>(xb, wvb, Vf, SEQ, DMODEL, DMODEL);

    rope_pack_kernel<<<SEQ * NHEADS * 32 / 256, 256, 0, stream>>>(Qf, Kf, Qh, Kh);
    pack_v_kernel<<<dim3(SEQ / 64, NHEADS), 256, 0, stream>>>(Vf, Vtb);

    attn_mfma_kernel<<<dim3(SEQ / 64, NHEADS), 256, 0, stream>>>(Qh, Kh, Vtb, ctxb);

    gemm_bt<0><<<gg, 256, 0, stream>>>(ctxb, wob, out, SEQ, DMODEL, DMODEL);
}